// Round 10
// baseline (92.176 us; speedup 1.0000x reference)
//
#include <hip/hip_runtime.h>
#include <cstdint>
#include <cmath>

#define BB 1024
#define CC 256
#define SS 64
#define DD 128
#define TOPKN 8
#define EPSF 1e-8f

typedef __attribute__((ext_vector_type(8))) short short8;
typedef __attribute__((ext_vector_type(16))) float f32x16;

static __device__ __forceinline__ unsigned short f2bf(float x) {
    uint32_t u = __float_as_uint(x);
    uint32_t r = (u + 0x7FFFu + ((u >> 16) & 1u)) >> 16;   // RNE
    return (unsigned short)r;
}
static __device__ __forceinline__ float bf2f(unsigned short h) {
    return __uint_as_float(((uint32_t)h) << 16);
}

// compare-exchange, descending (a keeps max)
#define CEX(a, b) { float _h = fmaxf(a, b), _l = fminf(a, b); (a) = _h; (b) = _l; }

// Batcher odd-even mergesort, 8 elems, descending. 19 comparators, depth 6.
static __device__ __forceinline__ void sort8(float* v) {
    CEX(v[0],v[1]); CEX(v[2],v[3]); CEX(v[4],v[5]); CEX(v[6],v[7]);
    CEX(v[0],v[2]); CEX(v[1],v[3]); CEX(v[4],v[6]); CEX(v[5],v[7]);
    CEX(v[1],v[2]); CEX(v[5],v[6]);
    CEX(v[0],v[4]); CEX(v[1],v[5]); CEX(v[2],v[6]); CEX(v[3],v[7]);
    CEX(v[2],v[4]); CEX(v[3],v[5]);
    CEX(v[1],v[2]); CEX(v[3],v[4]); CEX(v[5],v[6]);
}
// run := top-8 (sorted desc) of run ∪ cur; both sorted desc (bitonic top-k).
static __device__ __forceinline__ void merge8(float* run, const float* cur) {
    float t[8];
    #pragma unroll
    for (int i = 0; i < 8; i++) t[i] = fmaxf(run[i], cur[7 - i]);
    CEX(t[0],t[4]); CEX(t[1],t[5]); CEX(t[2],t[6]); CEX(t[3],t[7]);
    CEX(t[0],t[2]); CEX(t[1],t[3]); CEX(t[4],t[6]); CEX(t[5],t[7]);
    CEX(t[0],t[1]); CEX(t[2],t[3]); CEX(t[4],t[5]); CEX(t[6],t[7]);
    #pragma unroll
    for (int i = 0; i < 8; i++) run[i] = t[i];
}

// ---- kernel A: split emb (raw) and weight (row-normalized) into bf16 hi/lo
//      MFMA fragments + exact fp32 norms. (proven since R6) ----
__global__ __launch_bounds__(256) void split_kernel(const float* __restrict__ emb,
                                                    const float* __restrict__ weight,
                                                    unsigned short* __restrict__ ehi,
                                                    unsigned short* __restrict__ elo,
                                                    unsigned short* __restrict__ whi,
                                                    unsigned short* __restrict__ wlo,
                                                    float* __restrict__ nemb,
                                                    float* __restrict__ nw_g) {
    int gid = blockIdx.x * 256 + threadIdx.x;   // 16 threads per row
    int row = gid >> 4, kg = gid & 15;
    bool isEmb = row < BB;
    int r = isEmb ? row : row - BB;
    const float* src = isEmb ? emb : weight;
    const float4* sp = (const float4*)(src + (size_t)r * DD + kg * 8);
    float4 v0 = sp[0], v1 = sp[1];
    float x[8] = {v0.x, v0.y, v0.z, v0.w, v1.x, v1.y, v1.z, v1.w};
    float ss = 0.f;
    #pragma unroll
    for (int j = 0; j < 8; j++) ss += x[j] * x[j];
    #pragma unroll
    for (int off = 8; off; off >>= 1) ss += __shfl_xor(ss, off);

    float scale;
    if (isEmb) {
        if (kg == 0) nemb[r] = sqrtf(ss);
        scale = 1.0f;
    } else {
        if (kg == 0) nw_g[r] = sqrtf(ss);
        scale = 1.0f / sqrtf(fmaxf(ss, 1e-30f));
    }
    short8 h8, l8;
    #pragma unroll
    for (int j = 0; j < 8; j++) {
        float xs = x[j] * scale;
        unsigned short h = f2bf(xs);
        h8[j] = (short)h;
        l8[j] = (short)f2bf(xs - bf2f(h));
    }
    size_t o = ((size_t)(r >> 5) * 8 + (kg >> 1)) * 64 + (kg & 1) * 32 + (r & 31);
    if (isEmb) { ((short8*)ehi)[o] = h8; ((short8*)elo)[o] = l8; }
    else       { ((short8*)whi)[o] = h8; ((short8*)wlo)[o] = l8; }
}

// ---- kernel B (fused): one 36 KB LDS region, three lives:
//      (1) W[c] fragments  (2) dotL key staging  (3) Gs + per-thread queue.
//      37 KB/block -> 4 blocks/CU, grid 1024 = exactly 4 per CU (no tail). ----
__global__ __launch_bounds__(256, 4) void main_kernel(const unsigned short* __restrict__ ehi,
                                                      const unsigned short* __restrict__ elo,
                                                      const unsigned short* __restrict__ whi,
                                                      const unsigned short* __restrict__ wlo,
                                                      const float* __restrict__ nw_g,
                                                      const float* __restrict__ nemb,
                                                      float* __restrict__ out) {
    __shared__ __align__(16) float uni[256 * 36];   // 36 KB
    __shared__ float nwL[SS];
    short8* WsH = (short8*)uni;          // life 1: [ni(2)][t(8)][lane(64)], 16 KB
    short8* WsL = WsH + 1024;            //         +16 KB = 32 KB
    float (*dotL)[36] = (float(*)[36])uni;   // life 2: 36 KB (stride 36: 16B rows)
    float* Gs = uni;                     // life 3: 16 KB (written from gacc regs)

    int tid = threadIdx.x, lane = tid & 63, w = tid >> 6;
    int c = blockIdx.y, b0 = blockIdx.x * 256;

    // ---- life 1: stage W[c] fragments + nw[c] ----
    const short8* whg = (const short8*)whi + (size_t)c * 1024;
    const short8* wlg = (const short8*)wlo + (size_t)c * 1024;
    #pragma unroll
    for (int j = 0; j < 4; j++) {
        WsH[j * 256 + tid] = whg[j * 256 + tid];
        WsL[j * 256 + tid] = wlg[j * 256 + tid];
    }
    if (tid < SS) nwL[tid] = nw_g[c * SS + tid];
    __syncthreads();                                   // B1

    // ---- Gn quadrant (qi,qj) per wave -> gacc stays in 16 VGPRs ----
    int qi = w & 1, qj = w >> 1;
    f32x16 gacc = {};
    #pragma unroll
    for (int t = 0; t < 8; t++) {
        short8 ah = WsH[(qi * 8 + t) * 64 + lane];
        short8 al = WsL[(qi * 8 + t) * 64 + lane];
        short8 bh = WsH[(qj * 8 + t) * 64 + lane];
        short8 bl = WsL[(qj * 8 + t) * 64 + lane];
        gacc = __builtin_amdgcn_mfma_f32_32x32x16_bf16(ah, bh, gacc, 0, 0, 0);
        gacc = __builtin_amdgcn_mfma_f32_32x32x16_bf16(ah, bl, gacc, 0, 0, 0);
        gacc = __builtin_amdgcn_mfma_f32_32x32x16_bf16(al, bh, gacc, 0, 0, 0);
    }

    // ---- key GEMM: emb frags from global, W frags from LDS ----
    const short8* Ah = (const short8*)ehi;
    const short8* Al = (const short8*)elo;
    int mbase = blockIdx.x * 8 + w * 2;
    f32x16 acc[2][2] = {};
    #pragma unroll 2
    for (int t = 0; t < 8; t++) {
        short8 a_h[2], a_l[2];
        #pragma unroll
        for (int mi = 0; mi < 2; mi++) {
            size_t o = ((size_t)(mbase + mi) * 8 + t) * 64 + lane;
            a_h[mi] = Ah[o]; a_l[mi] = Al[o];
        }
        #pragma unroll
        for (int ni = 0; ni < 2; ni++) {       // B frags loaded per-ni: lower liveness
            short8 b_h = WsH[(ni * 8 + t) * 64 + lane];
            short8 b_l = WsL[(ni * 8 + t) * 64 + lane];
            #pragma unroll
            for (int mi = 0; mi < 2; mi++) {
                acc[mi][ni] = __builtin_amdgcn_mfma_f32_32x32x16_bf16(a_h[mi], b_h, acc[mi][ni], 0, 0, 0);
                acc[mi][ni] = __builtin_amdgcn_mfma_f32_32x32x16_bf16(a_h[mi], b_l, acc[mi][ni], 0, 0, 0);
                acc[mi][ni] = __builtin_amdgcn_mfma_f32_32x32x16_bf16(a_l[mi], b_h, acc[mi][ni], 0, 0, 0);
            }
        }
    }
    __syncthreads();                                   // B2: Ws dead

    // ---- life 2: key tile through LDS in two 32-s halves ----
    float key[SS];
    #pragma unroll
    for (int ni = 0; ni < 2; ni++) {
        #pragma unroll
        for (int mi = 0; mi < 2; mi++)
            #pragma unroll
            for (int r = 0; r < 16; r++) {
                int row = (r & 3) + 8 * (r >> 2) + 4 * (lane >> 5);
                dotL[w * 64 + mi * 32 + row][lane & 31] = acc[mi][ni][r];
            }
        __syncthreads();                               // B3 / B5
        #pragma unroll
        for (int j = 0; j < 8; j++) {                  // own-row b128 reads
            float4 v = *(const float4*)&dotL[tid][j * 4];
            key[ni * 32 + j * 4 + 0] = v.x; key[ni * 32 + j * 4 + 1] = v.y;
            key[ni * 32 + j * 4 + 2] = v.z; key[ni * 32 + j * 4 + 3] = v.w;
        }
        if (ni == 0) __syncthreads();                  // B4: rows reused by half 1
    }

    // ---- top-8 values via sorting networks (exact order statistics) ----
    float run[8], cur[8];
    #pragma unroll
    for (int i = 0; i < 8; i++) run[i] = key[i];
    sort8(run);
    #pragma unroll
    for (int g = 1; g < 8; g++) {
        #pragma unroll
        for (int i = 0; i < 8; i++) cur[i] = key[g * 8 + i];
        sort8(cur);
        merge8(run, cur);
    }
    float thresh = run[7];     // exact 8th largest

    // recover (key, idx): ascending s, first 8 >= thresh == lax.top_k tie set.
    // queue transiently overlays this thread's OWN dotL row, read back to regs
    // before Gs overwrites the region.
    float2* qp2 = (float2*)&dotL[tid][0];
    int cnt = 0;
    #pragma unroll
    for (int s = 0; s < SS; s++) {
        if (key[s] >= thresh && cnt < TOPKN) {
            qp2[cnt] = make_float2(key[s], (float)s);
            cnt++;
        }
    }
    float kq[TOPKN]; int idx[TOPKN];
    #pragma unroll
    for (int k = 0; k < TOPKN; k++) {
        float2 q = qp2[k];
        kq[k] = q.x;
        idx[k] = (int)q.y;
    }
    __syncthreads();                                   // B6: queues read everywhere

    // ---- life 3: write Gs from gacc regs ----
    #pragma unroll
    for (int r = 0; r < 16; r++) {
        int row = (r & 3) + 8 * (r >> 2) + 4 * (lane >> 5);
        Gs[(qi * 32 + row) * SS + qj * 32 + (lane & 31)] = gacc[r];
    }
    __syncthreads();                                   // B7

    // ---------------- epilogue math: 1 thread per b ----------------
    int b = b0 + tid;
    float ne = nemb[b];
    float inv_ne = 1.0f / ne;

    float sc0 = (1.0f + run[0] * inv_ne) * 0.5f + EPSF;
    float wk[TOPKN], wsum = 0.f;
    #pragma unroll
    for (int k = 0; k < TOPKN; k++) {
        float sck = (1.0f + kq[k] * inv_ne) * 0.5f + EPSF;
        float ev = __expf(sck - sc0);
        wk[k] = ev; wsum += ev;
    }
    float winv = 1.0f / wsum;

    float vk[TOPKN];
    #pragma unroll
    for (int k = 0; k < TOPKN; k++) vk[k] = wk[k] * nwL[idx[k]];
    float dot2 = 0.f;
    #pragma unroll
    for (int k = 0; k < TOPKN; k++) dot2 += vk[k] * kq[k];
    float np2 = 0.f;
    #pragma unroll
    for (int j = 0; j < TOPKN; j++) {
        float vj = vk[j];
        np2 += vj * vj * Gs[idx[j] * (SS + 1)];
        #pragma unroll
        for (int k2 = j + 1; k2 < TOPKN; k2++)
            np2 += 2.0f * vj * vk[k2] * Gs[idx[j] * SS + idx[k2]];
    }
    dot2 *= winv;
    np2 *= winv * winv;

    float denom2 = fmaxf(sqrtf(fmaxf(np2, 0.f)) * ne, EPSF);
    float cos2 = dot2 / denom2;
    out[(size_t)b * CC + c] = ((1.0f + cos2) * 0.5f + EPSF) / 0.1f;
}

extern "C" void kernel_launch(void* const* d_in, const int* in_sizes, int n_in,
                              void* d_out, int out_size, void* d_ws, size_t ws_size,
                              hipStream_t stream) {
    const float* emb    = (const float*)d_in[0];
    const float* weight = (const float*)d_in[1];
    float* nw   = (float*)d_ws;                                   // 64 KB
    float* nemb = nw + CC * SS;                                   // 4 KB
    unsigned short* ehi = (unsigned short*)(nemb + BB);           // 256 KB
    unsigned short* elo = ehi + (size_t)BB * DD;                  // 256 KB
    unsigned short* whi = elo + (size_t)BB * DD;                  // 4 MB
    unsigned short* wlo = whi + (size_t)CC * SS * DD;             // 4 MB
    float* out = (float*)d_out;

    hipLaunchKernelGGL(split_kernel, dim3((BB + CC * SS) * 16 / 256), dim3(256), 0, stream,
                       emb, weight, ehi, elo, whi, wlo, nemb, nw);
    hipLaunchKernelGGL(main_kernel, dim3(BB / 256, CC), dim3(256), 0, stream,
                       ehi, elo, whi, wlo, nw, nemb, out);
}